// Round 6
// baseline (386.614 us; speedup 1.0000x reference)
//
#include <hip/hip_runtime.h>
#include <cstdint>
#include <cstddef>

// Problem constants
#define DIMN 1024
#define SEQ  2048
#define NBAT 4
#define TOKS (NBAT * SEQ)   // 8192

typedef unsigned short u16;
typedef unsigned int   u32;

typedef __bf16 bf16x8 __attribute__((ext_vector_type(8)));
typedef float  f32x4  __attribute__((ext_vector_type(4)));

#define AS1 __attribute__((address_space(1)))
#define AS3 __attribute__((address_space(3)))

// ---- helpers ----------------------------------------------------------------

__device__ __forceinline__ u16 f2b(float f) {
  union { float f; u32 u; } v; v.f = f;
  u32 r = v.u + 0x7fffu + ((v.u >> 16) & 1u);   // round-to-nearest-even
  return (u16)(r >> 16);
}

__device__ __forceinline__ float b2f(u16 b) {
  union { u32 u; float f; } v; v.u = ((u32)b) << 16;
  return v.f;
}

__device__ __forceinline__ float gelu_exact(float v) {
  return 0.5f * v * (1.0f + erff(v * 0.70710678118654752f));
}

__device__ __forceinline__ void blk_sum2(float& a, float& b, float* sm) {
  #pragma unroll
  for (int o = 32; o >= 1; o >>= 1) {
    a += __shfl_xor(a, o, 64);
    b += __shfl_xor(b, o, 64);
  }
  int w = threadIdx.x >> 6;
  if ((threadIdx.x & 63) == 0) { sm[w] = a; sm[4 + w] = b; }
  __syncthreads();
  a = sm[0] + sm[1] + sm[2] + sm[3];
  b = sm[4] + sm[5] + sm[6] + sm[7];
  __syncthreads();
}

__device__ __forceinline__ float blk_max(float a, float* sm) {
  #pragma unroll
  for (int o = 32; o >= 1; o >>= 1) a = fmaxf(a, __shfl_xor(a, o, 64));
  int w = threadIdx.x >> 6;
  if ((threadIdx.x & 63) == 0) sm[w] = a;
  __syncthreads();
  float r = fmaxf(fmaxf(sm[0], sm[1]), fmaxf(sm[2], sm[3]));
  __syncthreads();
  return r;
}

__device__ __forceinline__ float blk_sum1(float a, float* sm) {
  #pragma unroll
  for (int o = 32; o >= 1; o >>= 1) a += __shfl_xor(a, o, 64);
  int w = threadIdx.x >> 6;
  if ((threadIdx.x & 63) == 0) sm[w] = a;
  __syncthreads();
  float r = sm[0] + sm[1] + sm[2] + sm[3];
  __syncthreads();
  return r;
}

// ---- prep: 5 weight transposes + x conversion, one dispatch -----------------
// z = 0..4 : W [K][N] f32 -> WT [N][K] bf16 (Wq/Wk/Wv into merged [3072][1024])
// z = 5    : x f32 -> bf16 (1024 xy-blocks x 8192 elems)
__global__ __launch_bounds__(256) void prep_all(
    const float* __restrict__ x,
    const float* __restrict__ Wq, const float* __restrict__ Wk,
    const float* __restrict__ Wv, const float* __restrict__ W1,
    const float* __restrict__ W2,
    u16* __restrict__ xb,
    u16* __restrict__ Wqkv, u16* __restrict__ W1T, u16* __restrict__ W2T)
{
  __shared__ float t[32][33];
  const int tx = threadIdx.x, ty = threadIdx.y;
  if (blockIdx.z == 5) {
    const int tid = ty * 32 + tx;
    const size_t base = ((size_t)(blockIdx.y * 32 + blockIdx.x)) * 8192;
    #pragma unroll
    for (int it = 0; it < 8; ++it) {
      size_t i = base + (size_t)(it * 256 + tid) * 4;
      float4 v = *(const float4*)(x + i);
      uint2 o;
      o.x = (u32)f2b(v.x) | ((u32)f2b(v.y) << 16);
      o.y = (u32)f2b(v.z) | ((u32)f2b(v.w) << 16);
      *(uint2*)(xb + i) = o;
    }
    return;
  }
  const float* W; u16* T;
  switch (blockIdx.z) {
    case 0: W = Wq; T = Wqkv;                   break;
    case 1: W = Wk; T = Wqkv + 1 * DIMN * DIMN; break;
    case 2: W = Wv; T = Wqkv + 2 * DIMN * DIMN; break;
    case 3: W = W1; T = W1T;                    break;
    default: W = W2; T = W2T;                   break;
  }
  int k0 = blockIdx.x * 32, n0 = blockIdx.y * 32;
  #pragma unroll
  for (int j = 0; j < 32; j += 8)
    t[ty + j][tx] = W[(size_t)(k0 + ty + j) * DIMN + n0 + tx];
  __syncthreads();
  #pragma unroll
  for (int j = 0; j < 32; j += 8)
    T[(size_t)(n0 + ty + j) * DIMN + k0 + tx] = f2b(t[tx][ty + j]);
}

// ---- MFMA GEMM: C[M,N] = A[M,K] * B^T  (B given as [N][K]) ------------------
// 128x128 tile, BK=64, 256 threads = 4 waves, wave tile 64x64 (4x4 of 16x16x32).
// Staging via global_load_lds width=16; XOR chunk swizzle (0 bank conflicts).
// SWZ=1 (tall GEMMs): bm-band per XCD (id%8), n-major traversal within band.
// EPI: 3 = QKV routed; Q/K plain bf16 (+bias); V-segment blocks transpose
//          their C-tile through LDS and store VT[b][d][tok] coalesced.
//      4 = +bias, GELU, bf16
//      6 = plain bf16
template <int EPI, int SWZ>
__global__ __launch_bounds__(256) void gemm_bt(
    const u16* __restrict__ A, const u16* __restrict__ Bm,
    u16* __restrict__ Cb, u16* __restrict__ Cb2, u16* __restrict__ Cb3,
    const float* __restrict__ bias, const float* __restrict__ bias2,
    const float* __restrict__ bias3,
    int M, int N, int K, int ldc,
    size_t sA, size_t sB, size_t sC)
{
  __shared__ u16 smem[2 * 128 * 64];   // 32 KiB: As | Bs; reused by V epilogue
  u16* As = smem;
  u16* Bs = smem + 128 * 64;

  const int tid = threadIdx.x;

  int bm0, bn0;
  if (SWZ == 1) {
    const int id   = blockIdx.y * gridDim.x + blockIdx.x;
    const int xcd  = id & 7;
    const int idx  = id >> 3;
    const int band = gridDim.x >> 3;          // bm rows per XCD
    bm0 = (xcd * band + idx % band) * 128;
    bn0 = (idx / band) * 128;
  } else {
    bm0 = blockIdx.x * 128;
    bn0 = blockIdx.y * 128;
  }

  A  += (size_t)blockIdx.z * sA;
  Bm += (size_t)blockIdx.z * sB;
  const int wave = tid >> 6, lane = tid & 63;
  const int wm   = (wave >> 1) * 64, wn = (wave & 1) * 64;
  const int l16  = lane & 15, quad = lane >> 4;

  f32x4 acc[4][4] = {};

  for (int k0 = 0; k0 < K; k0 += 64) {
    #pragma unroll
    for (int j = 0; j < 4; ++j) {
      const int c  = wave * 256 + j * 64 + lane;
      const int r  = c >> 3;
      const int cg = (c & 7) ^ (r & 7);
      const u16* gA = A  + (size_t)(bm0 + r) * K + k0 + cg * 8;
      const u16* gB = Bm + (size_t)(bn0 + r) * K + k0 + cg * 8;
      u16* lA = As + (wave * 4 + j) * 512;   // wave-uniform base, +lane*16B in HW
      u16* lB = Bs + (wave * 4 + j) * 512;
      __builtin_amdgcn_global_load_lds((const AS1 void*)gA, (AS3 void*)lA, 16, 0, 0);
      __builtin_amdgcn_global_load_lds((const AS1 void*)gB, (AS3 void*)lB, 16, 0, 0);
    }
    __syncthreads();

    #pragma unroll
    for (int kk = 0; kk < 64; kk += 32) {
      const int kc = kk >> 3;
      const int sw = l16 & 7;
      bf16x8 af[4], bfr[4];
      #pragma unroll
      for (int t = 0; t < 4; ++t) {
        const int row = wm + t * 16 + l16;
        af[t] = *(const bf16x8*)(&As[row * 64 + (((kc + quad) ^ sw) << 3)]);
      }
      #pragma unroll
      for (int t = 0; t < 4; ++t) {
        const int row = wn + t * 16 + l16;
        bfr[t] = *(const bf16x8*)(&Bs[row * 64 + (((kc + quad) ^ sw) << 3)]);
      }
      #pragma unroll
      for (int mt = 0; mt < 4; ++mt)
        #pragma unroll
        for (int nt = 0; nt < 4; ++nt)
          acc[mt][nt] = __builtin_amdgcn_mfma_f32_16x16x32_bf16(
              af[mt], bfr[nt], acc[mt][nt], 0, 0, 0);
    }
    __syncthreads();
  }

  // ---- epilogue: C/D layout col = lane&15, row = quad*4 + reg ----
  if (EPI == 3 && (bn0 >> 10) == 2) {
    // V segment: bias, then LDS-transpose the 128x128 tile, store VT coalesced.
    // LDS layout: elem (d_l, tok_l) at d_l*128 + ((tok_l>>3 ^ (d_l&7))<<3 | tok_l&7)
    #pragma unroll
    for (int mt = 0; mt < 4; ++mt) {
      const int tok_l0 = wm + mt * 16 + quad * 4;
      #pragma unroll
      for (int nt = 0; nt < 4; ++nt) {
        const int d_l = wn + nt * 16 + l16;
        const float bv = bias3[(bn0 & 1023) + d_l];
        ushort4 pk;
        pk.x = f2b(acc[mt][nt][0] + bv);
        pk.y = f2b(acc[mt][nt][1] + bv);
        pk.z = f2b(acc[mt][nt][2] + bv);
        pk.w = f2b(acc[mt][nt][3] + bv);
        // 4 consecutive tok in one 8-elem chunk (tok_l0 % 4 == 0)
        const int addr = d_l * 128 +
            ((((tok_l0 >> 3) ^ (d_l & 7)) << 3) | (tok_l0 & 7));
        *(ushort4*)(&smem[addr]) = pk;
      }
    }
    __syncthreads();
    const int b_idx = bm0 >> 11;        // batch (tile never crosses batch)
    const int tok0  = bm0 & 2047;
    const int d0    = bn0 & 1023;
    u16* dst = Cb3 + (size_t)b_idx * DIMN * SEQ;
    #pragma unroll
    for (int p = 0; p < 8; ++p) {
      const int idx = p * 256 + tid;
      const int row = idx >> 4, c = idx & 15;
      uint4 v = *(const uint4*)(&smem[row * 128 + ((c ^ (row & 7)) << 3)]);
      *(uint4*)(&dst[(size_t)(d0 + row) * SEQ + tok0 + c * 8]) = v;
    }
    return;
  }

  u16* Cbz = Cb + (size_t)blockIdx.z * sC;
  #pragma unroll
  for (int mt = 0; mt < 4; ++mt) {
    int grow0 = bm0 + wm + mt * 16 + quad * 4;
    #pragma unroll
    for (int nt = 0; nt < 4; ++nt) {
      int gcol = bn0 + wn + nt * 16 + l16;
      if (EPI == 3) {
        const int seg = gcol >> 10;           // 0 = Q, 1 = K here
        const int col = gcol & 1023;
        const float* bp = (seg == 0) ? bias : bias2;
        u16*         cp = (seg == 0) ? Cb   : Cb2;
        float bv = bp[col];
        #pragma unroll
        for (int r = 0; r < 4; ++r)
          cp[(size_t)(grow0 + r) * ldc + col] = f2b(acc[mt][nt][r] + bv);
      } else if (EPI == 4) {
        float bv = bias[gcol];
        #pragma unroll
        for (int r = 0; r < 4; ++r)
          Cbz[(size_t)(grow0 + r) * ldc + gcol] =
              f2b(gelu_exact(acc[mt][nt][r] + bv));
      } else {  // 6
        #pragma unroll
        for (int r = 0; r < 4; ++r)
          Cbz[(size_t)(grow0 + r) * ldc + gcol] = f2b(acc[mt][nt][r]);
      }
    }
  }
}

// ---- softmax over rows of 2048 (bf16 in), scale 1/8, write bf16 P -----------
__global__ __launch_bounds__(256) void softmax_rows(const u16* __restrict__ Sc,
                                                    u16* __restrict__ P) {
  __shared__ float sm[8];
  int row = blockIdx.x, t = threadIdx.x;
  const u16* s = Sc + (size_t)row * SEQ;
  uint4 raw = *(const uint4*)(s + t * 8);
  float v[8];
  #pragma unroll
  for (int m = 0; m < 4; ++m) {
    u32 w = ((const u32*)&raw)[m];
    v[2 * m]     = b2f((u16)(w & 0xffff)) * 0.125f;
    v[2 * m + 1] = b2f((u16)(w >> 16)) * 0.125f;
  }
  float mx = -1e30f;
  #pragma unroll
  for (int i = 0; i < 8; ++i) mx = fmaxf(mx, v[i]);
  mx = blk_max(mx, sm);
  float sum = 0.0f;
  #pragma unroll
  for (int i = 0; i < 8; ++i) { v[i] = __expf(v[i] - mx); sum += v[i]; }
  sum = blk_sum1(sum, sm);
  float inv = 1.0f / sum;
  uint4 o;
  #pragma unroll
  for (int m = 0; m < 4; ++m)
    ((u32*)&o)[m] = (u32)f2b(v[2 * m] * inv) | ((u32)f2b(v[2 * m + 1] * inv) << 16);
  *(uint4*)(P + (size_t)row * SEQ + t * 8) = o;
}

// ---- h = LN( LN(attn+x)*g_at+b_at + x )*g_ln+b_ln  -> hres bf16 -------------
__global__ __launch_bounds__(256) void ln1_fused(
    const u16* __restrict__ attn, const u16* __restrict__ xb,
    const float* __restrict__ g_at, const float* __restrict__ b_at,
    const float* __restrict__ g_ln, const float* __restrict__ b_ln,
    u16* __restrict__ hres)
{
  __shared__ float sm[8];
  int row = blockIdx.x, t = threadIdx.x;
  size_t base = (size_t)row * DIMN;
  uint2 ar = *(const uint2*)(attn + base + t * 4);
  uint2 xr4 = *(const uint2*)(xb + base + t * 4);
  float y[4], xr[4];
  float s = 0.0f, s2 = 0.0f;
  #pragma unroll
  for (int i = 0; i < 4; ++i) {
    u32 aw = ((const u32*)&ar)[i >> 1];
    u32 xw = ((const u32*)&xr4)[i >> 1];
    float av = b2f((u16)((i & 1) ? (aw >> 16) : (aw & 0xffff)));
    xr[i]    = b2f((u16)((i & 1) ? (xw >> 16) : (xw & 0xffff)));
    y[i] = av + xr[i];
    s += y[i]; s2 += y[i] * y[i];
  }
  blk_sum2(s, s2, sm);
  float m  = s * (1.0f / DIMN);
  float rs = rsqrtf(s2 * (1.0f / DIMN) - m * m + 1e-5f);
  float z[4];
  s = 0.0f; s2 = 0.0f;
  #pragma unroll
  for (int i = 0; i < 4; ++i) {
    int c = t * 4 + i;
    float at = (y[i] - m) * rs * g_at[c] + b_at[c];
    z[i] = at + xr[i];
    s += z[i]; s2 += z[i] * z[i];
  }
  blk_sum2(s, s2, sm);
  float m2  = s * (1.0f / DIMN);
  float rs2 = rsqrtf(s2 * (1.0f / DIMN) - m2 * m2 + 1e-5f);
  uint2 o;
  #pragma unroll
  for (int i = 0; i < 2; ++i) {
    int c = t * 4 + 2 * i;
    float h0 = (z[2 * i]     - m2) * rs2 * g_ln[c]     + b_ln[c];
    float h1 = (z[2 * i + 1] - m2) * rs2 * g_ln[c + 1] + b_ln[c + 1];
    ((u32*)&o)[i] = (u32)f2b(h0) | ((u32)f2b(h1) << 16);
  }
  *(uint2*)(hres + base + t * 4) = o;
}

// ---- out = LN(u + hres)*g_ln + b_ln  (bf16 in, f32 out) ---------------------
__global__ __launch_bounds__(256) void ln2_final(
    const u16* __restrict__ u, const u16* __restrict__ hres,
    const float* __restrict__ g, const float* __restrict__ bb,
    float* __restrict__ out)
{
  __shared__ float sm[8];
  int row = blockIdx.x, t = threadIdx.x;
  size_t base = (size_t)row * DIMN;
  uint2 ur = *(const uint2*)(u + base + t * 4);
  uint2 hr = *(const uint2*)(hres + base + t * 4);
  float y[4];
  float s = 0.0f, s2 = 0.0f;
  #pragma unroll
  for (int i = 0; i < 4; ++i) {
    u32 uw = ((const u32*)&ur)[i >> 1];
    u32 hw = ((const u32*)&hr)[i >> 1];
    float uv = b2f((u16)((i & 1) ? (uw >> 16) : (uw & 0xffff)));
    float hv = b2f((u16)((i & 1) ? (hw >> 16) : (hw & 0xffff)));
    y[i] = uv + hv;
    s += y[i]; s2 += y[i] * y[i];
  }
  blk_sum2(s, s2, sm);
  float m  = s * (1.0f / DIMN);
  float rs = rsqrtf(s2 * (1.0f / DIMN) - m * m + 1e-5f);
  float4 o;
  o.x = (y[0] - m) * rs * g[t * 4 + 0] + bb[t * 4 + 0];
  o.y = (y[1] - m) * rs * g[t * 4 + 1] + bb[t * 4 + 1];
  o.z = (y[2] - m) * rs * g[t * 4 + 2] + bb[t * 4 + 2];
  o.w = (y[3] - m) * rs * g[t * 4 + 3] + bb[t * 4 + 3];
  *(float4*)(out + base + t * 4) = o;
}

// ---- launch -----------------------------------------------------------------

extern "C" void kernel_launch(void* const* d_in, const int* in_sizes, int n_in,
                              void* d_out, int out_size, void* d_ws, size_t ws_size,
                              hipStream_t stream)
{
  const float* x    = (const float*)d_in[0];
  const float* Wq   = (const float*)d_in[1];
  const float* bq   = (const float*)d_in[2];
  const float* Wk   = (const float*)d_in[3];
  const float* bk   = (const float*)d_in[4];
  const float* Wv   = (const float*)d_in[5];
  const float* bv   = (const float*)d_in[6];
  const float* g_at = (const float*)d_in[7];
  const float* b_at = (const float*)d_in[8];
  const float* g_ln = (const float*)d_in[9];
  const float* b_ln = (const float*)d_in[10];
  const float* W1   = (const float*)d_in[11];
  const float* c1   = (const float*)d_in[12];
  const float* W2   = (const float*)d_in[13];
  const float* c2   = (const float*)d_in[14];
  float* out = (float*)d_out;

  // workspace layout (1 MiB units), peak 138 MiB (ws ~256 MiB confirmed r2):
  //   0..16   xb      (alive through ln1)
  //  16..18   W1T   18..20 W2T   20..26 WqkvT [3072][1024]
  //  26..42   Qb      (dead after scores)
  //  42..58   Kb      (dead after scores; tb alias for FFN mid)
  //  58..74   VT [b][d][tok]  (dead after PV; ub alias for FFN out)
  //  74..106  Sc bf16 (dead after softmax; attn 74..90, hres 90..106 alias)
  // 106..138  Pb bf16
  char* ws = (char*)d_ws;
  const size_t MB = 1u << 20;
  u16* xb    = (u16*)(ws + 0 * MB);
  u16* W1T   = (u16*)(ws + 16 * MB);
  u16* W2T   = (u16*)(ws + 18 * MB);
  u16* WqkvT = (u16*)(ws + 20 * MB);
  u16* Qb    = (u16*)(ws + 26 * MB);
  u16* Kb    = (u16*)(ws + 42 * MB);
  u16* VT    = (u16*)(ws + 58 * MB);
  u16* Sc    = (u16*)(ws + 74 * MB);
  u16* attn  = (u16*)(ws + 74 * MB);
  u16* hres  = (u16*)(ws + 90 * MB);
  u16* Pb    = (u16*)(ws + 106 * MB);
  u16* tb    = Kb;   // FFN mid, K dead
  u16* ub    = VT;   // FFN out, VT dead after PV

  // prep: x conversion + all weight transposes, one dispatch
  prep_all<<<dim3(32, 32, 6), dim3(32, 8), 0, stream>>>(
      x, Wq, Wk, Wv, W1, W2, xb, WqkvT, W1T, W2T);

  // fused QKV projection: [8192,1024] @ [3072,1024]^T, bm-band swizzle.
  // V-segment epilogue writes VT[b][d][tok] directly (LDS transpose).
  gemm_bt<3, 1><<<dim3(64, 24), 256, 0, stream>>>(
      xb, WqkvT, Qb, Kb, VT, bq, bk, bv,
      TOKS, 3 * DIMN, DIMN, DIMN, 0, 0, 0);

  // scores (bf16 out), batched over grid.z, natural order
  gemm_bt<6, 0><<<dim3(16, 16, NBAT), 256, 0, stream>>>(
      Qb, Kb, Sc, nullptr, nullptr, nullptr, nullptr, nullptr,
      SEQ, SEQ, DIMN, SEQ,
      (size_t)SEQ * DIMN, (size_t)SEQ * DIMN, (size_t)SEQ * SEQ);
  softmax_rows<<<TOKS, 256, 0, stream>>>(Sc, Pb);
  gemm_bt<6, 0><<<dim3(16, 8, NBAT), 256, 0, stream>>>(
      Pb, VT, attn, nullptr, nullptr, nullptr, nullptr, nullptr,
      SEQ, DIMN, SEQ, DIMN,
      (size_t)SEQ * SEQ, (size_t)DIMN * SEQ, (size_t)SEQ * DIMN);

  // h = LN(LN(attn+x)+x) -> hres bf16 (serves GEMM A and final residual)
  ln1_fused<<<TOKS, 256, 0, stream>>>(attn, xb, g_at, b_at, g_ln, b_ln, hres);

  // FFN (bm-band swizzle)
  gemm_bt<4, 1><<<dim3(64, 8), 256, 0, stream>>>(
      hres, W1T, tb, nullptr, nullptr, c1, nullptr, nullptr,
      TOKS, DIMN, DIMN, DIMN, 0, 0, 0);
  gemm_bt<4, 1><<<dim3(64, 8), 256, 0, stream>>>(
      tb, W2T, ub, nullptr, nullptr, c2, nullptr, nullptr,
      TOKS, DIMN, DIMN, DIMN, 0, 0, 0);

  // out = LN(u + h)
  ln2_final<<<TOKS, 256, 0, stream>>>(ub, hres, g_ln, b_ln, out);
}